// Round 1
// baseline (1436.675 us; speedup 1.0000x reference)
//
#include <hip/hip_runtime.h>
#include <hip/hip_bf16.h>

#define DM 1024
#define QLEN 512
#define VLEN 80
#define BQTOT 32768   // B*Q
#define BVTOT 5120    // B*V

typedef __attribute__((ext_vector_type(8))) short s16x8;
typedef __attribute__((ext_vector_type(4))) short s16x4;
typedef __attribute__((ext_vector_type(4))) float f32x4;
typedef __attribute__((ext_vector_type(8))) __bf16 bf16x8;

__device__ inline short f2bf(float f) {
    __bf16 h = (__bf16)f;
    return __builtin_bit_cast(short, h);
}
__device__ inline float bf2f(short s) {
    unsigned u = ((unsigned)(unsigned short)s) << 16;
    return __builtin_bit_cast(float, u);
}

// ---------------- weight transpose + bf16 convert: W[K][N] -> WT[N][K] ----------------
__global__ __launch_bounds__(256)
void transp_k(const float* __restrict__ W, short* __restrict__ WT, int K, int N)
{
    __shared__ float s[32][33];
    const int n0 = blockIdx.x * 32, k0 = blockIdx.y * 32;
    const int tx = threadIdx.x & 31, ty = threadIdx.x >> 5;
#pragma unroll
    for (int j = 0; j < 4; j++)
        s[ty + j * 8][tx] = W[(size_t)(k0 + ty + j * 8) * N + n0 + tx];
    __syncthreads();
#pragma unroll
    for (int j = 0; j < 4; j++) {
        int r = ty + j * 8;
        WT[(size_t)(n0 + r) * K + k0 + tx] = f2bf(s[tx][r]);
    }
}

// ---------------- tiled bf16 MFMA GEMM ----------------
// C[M][N] = A[M][K] * BT[N][K]^T (+ bias / residual per EPI)
// ASRC: 0 = A is fp32 (convert during staging), 1 = A is bf16
// EPI:  0 = bf16 out = acc+bias
//       1 = bf16 out = relu(acc+bias)
//       2 = f32 out = acc+bias+resid_f32
//       3 = f32 out = acc+bias+resid_bf16
//       4 = f32 out = acc+resid_f32 (no bias)
#define BM 128
#define BN 128
#define BKT 32
#define LDT 40   // padded LDS row stride (bf16 elems)

template<int ASRC, int EPI>
__global__ __launch_bounds__(256)
void gemm_k(const void* __restrict__ Ap, const short* __restrict__ BT,
            const float* __restrict__ bias, const void* __restrict__ resid,
            void* __restrict__ outp, int M, int N, int K, int lda, int ldb)
{
    __shared__ __align__(16) short As[BM * LDT];
    __shared__ __align__(16) short Bs[BN * LDT];

    const int tid = threadIdx.x;
    const int lane = tid & 63;
    const int wid = tid >> 6;
    const int wr = wid >> 1, wc = wid & 1;
    const int m0 = blockIdx.y * BM;
    const int n0 = blockIdx.x * BN;

    f32x4 acc[4][4];
#pragma unroll
    for (int i = 0; i < 4; i++)
#pragma unroll
        for (int j = 0; j < 4; j++) acc[i][j] = (f32x4){0.f, 0.f, 0.f, 0.f};

    const int kl = (lane >> 4) * 8;        // k offset of this lane's fragment
    const int rA = wr * 64 + (lane & 15);  // A row within tile
    const int rB = wc * 64 + (lane & 15);  // B col (= BT row) within tile

    for (int k0 = 0; k0 < K; k0 += BKT) {
        if (ASRC == 0) {
            const float* A = (const float*)Ap;
#pragma unroll
            for (int i = 0; i < 4; i++) {
                int flat = tid + i * 256;           // float4 units, 0..1023
                int row = flat >> 3, c4 = flat & 7;
                const float4 v = *(const float4*)(A + (size_t)(m0 + row) * lda + k0 + c4 * 4);
                s16x4 p; p[0] = f2bf(v.x); p[1] = f2bf(v.y); p[2] = f2bf(v.z); p[3] = f2bf(v.w);
                *(s16x4*)&As[row * LDT + c4 * 4] = p;
            }
        } else {
            const short* A = (const short*)Ap;
#pragma unroll
            for (int i = 0; i < 2; i++) {
                int flat = tid + i * 256;           // short8 units, 0..511
                int row = flat >> 2, c8 = flat & 3;
                *(s16x8*)&As[row * LDT + c8 * 8] =
                    *(const s16x8*)(A + (size_t)(m0 + row) * lda + k0 + c8 * 8);
            }
        }
#pragma unroll
        for (int i = 0; i < 2; i++) {
            int flat = tid + i * 256;
            int row = flat >> 2, c8 = flat & 3;
            *(s16x8*)&Bs[row * LDT + c8 * 8] =
                *(const s16x8*)(BT + (size_t)(n0 + row) * ldb + k0 + c8 * 8);
        }
        __syncthreads();

        bf16x8 af[4], bfr[4];
#pragma unroll
        for (int m = 0; m < 4; m++)
            af[m] = *(const bf16x8*)&As[(rA + m * 16) * LDT + kl];
#pragma unroll
        for (int n = 0; n < 4; n++)
            bfr[n] = *(const bf16x8*)&Bs[(rB + n * 16) * LDT + kl];
#pragma unroll
        for (int m = 0; m < 4; m++)
#pragma unroll
            for (int n = 0; n < 4; n++)
                acc[m][n] = __builtin_amdgcn_mfma_f32_16x16x32_bf16(af[m], bfr[n], acc[m][n], 0, 0, 0);
        __syncthreads();
    }

    const int rbase = m0 + wr * 64 + ((lane >> 4) << 2);
    const int cbase = n0 + wc * 64 + (lane & 15);
#pragma unroll
    for (int m = 0; m < 4; m++) {
#pragma unroll
        for (int n = 0; n < 4; n++) {
            const int gn = cbase + n * 16;
            const float bb = (EPI == 4) ? 0.f : bias[gn];
#pragma unroll
            for (int r = 0; r < 4; r++) {
                const int gm = rbase + m * 16 + r;
                const size_t oidx = (size_t)gm * N + gn;
                float v = acc[m][n][r] + bb;
                if (EPI == 0) {
                    ((short*)outp)[oidx] = f2bf(v);
                } else if (EPI == 1) {
                    ((short*)outp)[oidx] = f2bf(fmaxf(v, 0.f));
                } else if (EPI == 2 || EPI == 4) {
                    ((float*)outp)[oidx] = v + ((const float*)resid)[oidx];
                } else { // EPI == 3
                    ((float*)outp)[oidx] = v + bf2f(((const short*)resid)[oidx]);
                }
            }
        }
    }
}

// ---------------- sparse 2-key attention gather ----------------
// one wave per (b,q); lane owns 16 consecutive channels; head = lane>>3
__global__ __launch_bounds__(64)
void attn_k(const short* __restrict__ Qb, const short* __restrict__ Kb,
            const short* __restrict__ Vb, const int* __restrict__ rel,
            short* __restrict__ ctx)
{
    const int bq = blockIdx.x;
    const int b = bq >> 9;           // Q = 512
    const int lane = threadIdx.x;
    const int v0 = rel[bq * 2 + 0];
    const int v1 = rel[bq * 2 + 1];
    const short* qr  = Qb + (size_t)bq * DM;
    const short* k0r = Kb + (size_t)(b * VLEN + v0) * DM;
    const short* k1r = Kb + (size_t)(b * VLEN + v1) * DM;
    const short* v0r = Vb + (size_t)(b * VLEN + v0) * DM;
    const short* v1r = Vb + (size_t)(b * VLEN + v1) * DM;
    const int d0 = lane * 16;

    float q[16], ka[16], kc[16];
    {
        s16x8 a = *(const s16x8*)(qr + d0);
        s16x8 c = *(const s16x8*)(qr + d0 + 8);
#pragma unroll
        for (int i = 0; i < 8; i++) { q[i] = bf2f(a[i]); q[8 + i] = bf2f(c[i]); }
        a = *(const s16x8*)(k0r + d0); c = *(const s16x8*)(k0r + d0 + 8);
#pragma unroll
        for (int i = 0; i < 8; i++) { ka[i] = bf2f(a[i]); ka[8 + i] = bf2f(c[i]); }
        a = *(const s16x8*)(k1r + d0); c = *(const s16x8*)(k1r + d0 + 8);
#pragma unroll
        for (int i = 0; i < 8; i++) { kc[i] = bf2f(a[i]); kc[8 + i] = bf2f(c[i]); }
    }
    float s0 = 0.f, s1 = 0.f;
#pragma unroll
    for (int i = 0; i < 16; i++) { s0 += q[i] * ka[i]; s1 += q[i] * kc[i]; }
    // reduce across the 8 lanes of this head (128 channels / 16 per lane)
#pragma unroll
    for (int m = 1; m < 8; m <<= 1) { s0 += __shfl_xor(s0, m); s1 += __shfl_xor(s1, m); }
    const float sc = 0.08838834764831845f; // 1/sqrt(128)
    s0 *= sc; s1 *= sc;
    const float mx = fmaxf(s0, s1);
    const float e0 = __expf(s0 - mx), e1 = __expf(s1 - mx);
    const float inv = 1.f / (e0 + e1);
    const float w0 = e0 * inv, w1 = e1 * inv;

    float va[16], vb[16];
    {
        s16x8 a = *(const s16x8*)(v0r + d0); s16x8 c = *(const s16x8*)(v0r + d0 + 8);
#pragma unroll
        for (int i = 0; i < 8; i++) { va[i] = bf2f(a[i]); va[8 + i] = bf2f(c[i]); }
        a = *(const s16x8*)(v1r + d0); c = *(const s16x8*)(v1r + d0 + 8);
#pragma unroll
        for (int i = 0; i < 8; i++) { vb[i] = bf2f(a[i]); vb[8 + i] = bf2f(c[i]); }
    }
    s16x8 pa, pb;
#pragma unroll
    for (int i = 0; i < 8; i++) {
        pa[i] = f2bf(w0 * va[i] + w1 * vb[i]);
        pb[i] = f2bf(w0 * va[8 + i] + w1 * vb[8 + i]);
    }
    short* o = ctx + (size_t)bq * DM + d0;
    *(s16x8*)o = pa;
    *(s16x8*)(o + 8) = pb;
}

// ---------------- LayerNorm over rows of 1024 ----------------
// OUTBF=1: write bf16; OUTBF=0: write f32 (may be in-place with input)
template<int OUTBF>
__global__ __launch_bounds__(256)
void ln_k(const float* __restrict__ in, const float* __restrict__ g,
          const float* __restrict__ bv, void* __restrict__ outp)
{
    const int row = blockIdx.x;
    const int tid = threadIdx.x;
    const float* x = in + (size_t)row * DM;
    const float4 v = *(const float4*)(x + tid * 4);
    float s = v.x + v.y + v.z + v.w;
    float ss = v.x * v.x + v.y * v.y + v.z * v.z + v.w * v.w;
#pragma unroll
    for (int m = 1; m < 64; m <<= 1) { s += __shfl_xor(s, m); ss += __shfl_xor(ss, m); }
    __shared__ float red[8];
    if ((tid & 63) == 0) { red[tid >> 6] = s; red[4 + (tid >> 6)] = ss; }
    __syncthreads();
    const float S = red[0] + red[1] + red[2] + red[3];
    const float SS = red[4] + red[5] + red[6] + red[7];
    const float mean = S * (1.f / DM);
    const float var = SS * (1.f / DM) - mean * mean;
    const float rstd = rsqrtf(var + 1e-5f);
    float y[4];
#pragma unroll
    for (int j = 0; j < 4; j++) {
        const int c = tid * 4 + j;
        const float xv = (j == 0) ? v.x : (j == 1) ? v.y : (j == 2) ? v.z : v.w;
        y[j] = (xv - mean) * rstd * g[c] + bv[c];
    }
    if (OUTBF) {
        s16x4 p; p[0] = f2bf(y[0]); p[1] = f2bf(y[1]); p[2] = f2bf(y[2]); p[3] = f2bf(y[3]);
        *(s16x4*)((short*)outp + (size_t)row * DM + tid * 4) = p;
    } else {
        float4 o; o.x = y[0]; o.y = y[1]; o.z = y[2]; o.w = y[3];
        *(float4*)((float*)outp + (size_t)row * DM + tid * 4) = o;
    }
}

extern "C" void kernel_launch(void* const* d_in, const int* in_sizes, int n_in,
                              void* d_out, int out_size, void* d_ws, size_t ws_size,
                              hipStream_t stream)
{
    const float* pred = (const float*)d_in[0];
    const float* ent  = (const float*)d_in[1];
    const int*   rel  = (const int*)d_in[2];
    const float* w_q  = (const float*)d_in[3];
    const float* b_q  = (const float*)d_in[4];
    const float* w_k  = (const float*)d_in[5];
    const float* b_k  = (const float*)d_in[6];
    const float* w_v  = (const float*)d_in[7];
    const float* b_v  = (const float*)d_in[8];
    const float* w_o  = (const float*)d_in[9];
    const float* b_o  = (const float*)d_in[10];
    const float* ln1g = (const float*)d_in[11];
    const float* ln1b = (const float*)d_in[12];
    const float* w1   = (const float*)d_in[13];
    const float* b1   = (const float*)d_in[14];
    const float* w2   = (const float*)d_in[15];
    const float* b2   = (const float*)d_in[16];
    const float* ln2g = (const float*)d_in[17];
    const float* ln2b = (const float*)d_in[18];

    char* ws = (char*)d_ws;
    size_t off = 0;
    auto alloc = [&](size_t bytes) -> char* {
        char* p = ws + off;
        off += (bytes + 255) & ~(size_t)255;
        return p;
    };
    short* wqT = (short*)alloc((size_t)1024 * 1024 * 2);
    short* wkT = (short*)alloc((size_t)1024 * 1024 * 2);
    short* wvT = (short*)alloc((size_t)1024 * 1024 * 2);
    short* woT = (short*)alloc((size_t)1024 * 1024 * 2);
    short* w1T = (short*)alloc((size_t)4096 * 1024 * 2);   // [4096][1024]
    short* w2T = (short*)alloc((size_t)1024 * 4096 * 2);   // [1024][4096]
    short* Kb  = (short*)alloc((size_t)BVTOT * DM * 2);
    short* Vb  = (short*)alloc((size_t)BVTOT * DM * 2);
    short* CTX = (short*)alloc((size_t)BQTOT * DM * 2);    // later reused as Xb
    short* BIG = (short*)alloc((size_t)BQTOT * 2048 * 2);  // Qb first, then H-half
    short* Qb  = BIG;
    short* H0  = BIG;
    short* Xb  = CTX;
    float* P   = (float*)d_out;   // fp32 pre-LN buffer lives in d_out

    // ---- weight transposes (fp32 -> bf16, [K][N] -> [N][K]) ----
    transp_k<<<dim3(32, 32), 256, 0, stream>>>(w_q, wqT, 1024, 1024);
    transp_k<<<dim3(32, 32), 256, 0, stream>>>(w_k, wkT, 1024, 1024);
    transp_k<<<dim3(32, 32), 256, 0, stream>>>(w_v, wvT, 1024, 1024);
    transp_k<<<dim3(32, 32), 256, 0, stream>>>(w_o, woT, 1024, 1024);
    transp_k<<<dim3(128, 32), 256, 0, stream>>>(w1, w1T, 1024, 4096);
    transp_k<<<dim3(32, 128), 256, 0, stream>>>(w2, w2T, 4096, 1024);

    // ---- projections (bf16 out) ----
    gemm_k<0, 0><<<dim3(8, 256), 256, 0, stream>>>(pred, wqT, b_q, nullptr, Qb,
                                                   BQTOT, 1024, 1024, 1024, 1024);
    gemm_k<0, 0><<<dim3(8, 40), 256, 0, stream>>>(ent, wkT, b_k, nullptr, Kb,
                                                  BVTOT, 1024, 1024, 1024, 1024);
    gemm_k<0, 0><<<dim3(8, 40), 256, 0, stream>>>(ent, wvT, b_v, nullptr, Vb,
                                                  BVTOT, 1024, 1024, 1024, 1024);

    // ---- sparse attention (2 allowed keys per query) ----
    attn_k<<<BQTOT, 64, 0, stream>>>(Qb, Kb, Vb, rel, CTX);

    // ---- output proj + residual -> P (f32), then LN1 -> Xb (bf16) ----
    gemm_k<1, 2><<<dim3(8, 256), 256, 0, stream>>>(CTX, woT, b_o, pred, P,
                                                   BQTOT, 1024, 1024, 1024, 1024);
    ln_k<1><<<BQTOT, 256, 0, stream>>>(P, ln1g, ln1b, Xb);

    // ---- FFN, split into two D_INNER halves to bound workspace ----
    // half 0
    gemm_k<1, 1><<<dim3(16, 256), 256, 0, stream>>>(Xb, w1T, b1, nullptr, H0,
                                                    BQTOT, 2048, 1024, 1024, 1024);
    gemm_k<1, 3><<<dim3(8, 256), 256, 0, stream>>>(H0, w2T, b2, Xb, P,
                                                   BQTOT, 1024, 2048, 2048, 4096);
    // half 1 (accumulate into P)
    gemm_k<1, 1><<<dim3(16, 256), 256, 0, stream>>>(Xb, w1T + (size_t)2048 * 1024, b1 + 2048,
                                                    nullptr, H0,
                                                    BQTOT, 2048, 1024, 1024, 1024);
    gemm_k<1, 4><<<dim3(8, 256), 256, 0, stream>>>(H0, w2T + 2048, b2, P, P,
                                                   BQTOT, 1024, 2048, 2048, 4096);

    // ---- LN2 in place -> d_out ----
    ln_k<0><<<BQTOT, 256, 0, stream>>>(P, ln2g, ln2b, P);
}

// Round 2
// 1416.965 us; speedup vs baseline: 1.0139x; 1.0139x over previous
//
#include <hip/hip_runtime.h>
#include <hip/hip_bf16.h>

#define DM 1024
#define QLEN 512
#define VLEN 80
#define BQTOT 32768   // B*Q
#define BVTOT 5120    // B*V

typedef __attribute__((ext_vector_type(8))) short s16x8;
typedef __attribute__((ext_vector_type(4))) short s16x4;
typedef __attribute__((ext_vector_type(4))) float f32x4;
typedef __attribute__((ext_vector_type(8))) __bf16 bf16x8;

__device__ inline short f2bf(float f) {
    __bf16 h = (__bf16)f;
    return __builtin_bit_cast(short, h);
}
__device__ inline float bf2f(short s) {
    unsigned u = ((unsigned)(unsigned short)s) << 16;
    return __builtin_bit_cast(float, u);
}

// ---------------- fp32 -> bf16 bulk convert (8 elems/thread) ----------------
__global__ __launch_bounds__(256)
void conv_k(const float* __restrict__ in, short* __restrict__ out, int n8)
{
    const int i = blockIdx.x * 256 + threadIdx.x;
    if (i >= n8) return;
    const float4 a = ((const float4*)in)[(size_t)i * 2];
    const float4 b = ((const float4*)in)[(size_t)i * 2 + 1];
    s16x8 p;
    p[0] = f2bf(a.x); p[1] = f2bf(a.y); p[2] = f2bf(a.z); p[3] = f2bf(a.w);
    p[4] = f2bf(b.x); p[5] = f2bf(b.y); p[6] = f2bf(b.z); p[7] = f2bf(b.w);
    ((s16x8*)out)[i] = p;
}

// ---------------- weight transpose + bf16 convert: W[K][N] -> WT[N][K] ----------------
__global__ __launch_bounds__(256)
void transp_k(const float* __restrict__ W, short* __restrict__ WT, int K, int N)
{
    __shared__ float s[32][33];
    const int n0 = blockIdx.x * 32, k0 = blockIdx.y * 32;
    const int tx = threadIdx.x & 31, ty = threadIdx.x >> 5;
#pragma unroll
    for (int j = 0; j < 4; j++)
        s[ty + j * 8][tx] = W[(size_t)(k0 + ty + j * 8) * N + n0 + tx];
    __syncthreads();
#pragma unroll
    for (int j = 0; j < 4; j++) {
        int r = ty + j * 8;
        WT[(size_t)(n0 + r) * K + k0 + tx] = f2bf(s[tx][r]);
    }
}

// ---------------- m97-style bf16 MFMA GEMM ----------------
// C[M][N] = A[M][K] * BT[N][K]^T (+ bias / residual per EPI)
// A is bf16. Staging via global_load_lds width=16, linear LDS, BK=64.
// Grid: 1D, XCD-swizzled; NT = number of N tiles.
// EPI:  0 = bf16 out = acc+bias
//       1 = bf16 out = relu(acc+bias)
//       2 = f32 out = acc+bias+resid_f32
//       3 = f32 out = acc+bias+resid_bf16
//       4 = f32 out = acc+resid_f32 (no bias)
#define GBM 128
#define GBN 128
#define GBK 64

template<int EPI>
__global__ __launch_bounds__(256)
void gemm2_k(const short* __restrict__ A, const short* __restrict__ BT,
             const float* __restrict__ bias, const void* __restrict__ resid,
             void* __restrict__ outp, int M, int N, int K, int lda, int ldb, int NT)
{
    __shared__ __align__(16) short As[GBM * GBK];
    __shared__ __align__(16) short Bs[GBN * GBK];

    const int tid = threadIdx.x;
    const int lane = tid & 63;
    const int wid = tid >> 6;
    const int wr = wid >> 1, wc = wid & 1;

    // bijective XCD swizzle (nwg % 8 == 0 for all launches here)
    const int nwg = gridDim.x;
    const int f = blockIdx.x;
    const int logical = (f & 7) * (nwg >> 3) + (f >> 3);
    const int m0 = (logical / NT) * GBM;
    const int n0 = (logical % NT) * GBN;

    f32x4 acc[4][4];
#pragma unroll
    for (int i = 0; i < 4; i++)
#pragma unroll
        for (int j = 0; j < 4; j++) acc[i][j] = (f32x4){0.f, 0.f, 0.f, 0.f};

    // staging geometry: 16 chunks of 1 KiB per tile; wave w owns chunks w*4..w*4+3
    // chunk covers 8 rows x 64 bf16; lane l -> row chunk*8 + (l>>3), col (l&7)*8
    const int chunk0 = wid * 4;
    const int rowInChunk = lane >> 3;
    const int colOff = (lane & 7) * 8;

    const short* gA = A + (size_t)m0 * lda;
    const short* gB = BT + (size_t)n0 * ldb;

    const int rA = wr * 64 + (lane & 15);
    const int rB = wc * 64 + (lane & 15);
    const int klo = (lane >> 4) * 8;

    for (int k0 = 0; k0 < K; k0 += GBK) {
#pragma unroll
        for (int i = 0; i < 4; i++) {
            const int ch = chunk0 + i;
            const int row = ch * 8 + rowInChunk;
            __builtin_amdgcn_global_load_lds(
                (const __attribute__((address_space(1))) void*)(gA + (size_t)row * lda + k0 + colOff),
                (__attribute__((address_space(3))) void*)(&As[ch * 512]),
                16, 0, 0);
            __builtin_amdgcn_global_load_lds(
                (const __attribute__((address_space(1))) void*)(gB + (size_t)row * ldb + k0 + colOff),
                (__attribute__((address_space(3))) void*)(&Bs[ch * 512]),
                16, 0, 0);
        }
        __syncthreads();

#pragma unroll
        for (int ks = 0; ks < 2; ks++) {
            bf16x8 af[4], bfr[4];
#pragma unroll
            for (int m = 0; m < 4; m++)
                af[m] = *(const bf16x8*)&As[(rA + m * 16) * GBK + ks * 32 + klo];
#pragma unroll
            for (int n = 0; n < 4; n++)
                bfr[n] = *(const bf16x8*)&Bs[(rB + n * 16) * GBK + ks * 32 + klo];
#pragma unroll
            for (int m = 0; m < 4; m++)
#pragma unroll
                for (int n = 0; n < 4; n++)
                    acc[m][n] = __builtin_amdgcn_mfma_f32_16x16x32_bf16(af[m], bfr[n], acc[m][n], 0, 0, 0);
        }
        __syncthreads();
    }

    const int rbase = m0 + wr * 64 + ((lane >> 4) << 2);
    const int cbase = n0 + wc * 64 + (lane & 15);
#pragma unroll
    for (int m = 0; m < 4; m++) {
#pragma unroll
        for (int n = 0; n < 4; n++) {
            const int gn = cbase + n * 16;
            const float bb = (EPI == 4) ? 0.f : bias[gn];
#pragma unroll
            for (int r = 0; r < 4; r++) {
                const int gm = rbase + m * 16 + r;
                const size_t oidx = (size_t)gm * N + gn;
                float v = acc[m][n][r] + bb;
                if (EPI == 0) {
                    ((short*)outp)[oidx] = f2bf(v);
                } else if (EPI == 1) {
                    ((short*)outp)[oidx] = f2bf(fmaxf(v, 0.f));
                } else if (EPI == 2 || EPI == 4) {
                    ((float*)outp)[oidx] = v + ((const float*)resid)[oidx];
                } else { // EPI == 3
                    ((float*)outp)[oidx] = v + bf2f(((const short*)resid)[oidx]);
                }
            }
        }
    }
}

// ---------------- sparse 2-key attention gather ----------------
__global__ __launch_bounds__(64)
void attn_k(const short* __restrict__ Qb, const short* __restrict__ Kb,
            const short* __restrict__ Vb, const int* __restrict__ rel,
            short* __restrict__ ctx)
{
    const int bq = blockIdx.x;
    const int b = bq >> 9;           // Q = 512
    const int lane = threadIdx.x;
    const int v0 = rel[bq * 2 + 0];
    const int v1 = rel[bq * 2 + 1];
    const short* qr  = Qb + (size_t)bq * DM;
    const short* k0r = Kb + (size_t)(b * VLEN + v0) * DM;
    const short* k1r = Kb + (size_t)(b * VLEN + v1) * DM;
    const short* v0r = Vb + (size_t)(b * VLEN + v0) * DM;
    const short* v1r = Vb + (size_t)(b * VLEN + v1) * DM;
    const int d0 = lane * 16;

    float q[16], ka[16], kc[16];
    {
        s16x8 a = *(const s16x8*)(qr + d0);
        s16x8 c = *(const s16x8*)(qr + d0 + 8);
#pragma unroll
        for (int i = 0; i < 8; i++) { q[i] = bf2f(a[i]); q[8 + i] = bf2f(c[i]); }
        a = *(const s16x8*)(k0r + d0); c = *(const s16x8*)(k0r + d0 + 8);
#pragma unroll
        for (int i = 0; i < 8; i++) { ka[i] = bf2f(a[i]); ka[8 + i] = bf2f(c[i]); }
        a = *(const s16x8*)(k1r + d0); c = *(const s16x8*)(k1r + d0 + 8);
#pragma unroll
        for (int i = 0; i < 8; i++) { kc[i] = bf2f(a[i]); kc[8 + i] = bf2f(c[i]); }
    }
    float s0 = 0.f, s1 = 0.f;
#pragma unroll
    for (int i = 0; i < 16; i++) { s0 += q[i] * ka[i]; s1 += q[i] * kc[i]; }
#pragma unroll
    for (int m = 1; m < 8; m <<= 1) { s0 += __shfl_xor(s0, m); s1 += __shfl_xor(s1, m); }
    const float sc = 0.08838834764831845f; // 1/sqrt(128)
    s0 *= sc; s1 *= sc;
    const float mx = fmaxf(s0, s1);
    const float e0 = __expf(s0 - mx), e1 = __expf(s1 - mx);
    const float inv = 1.f / (e0 + e1);
    const float w0 = e0 * inv, w1 = e1 * inv;

    float va[16], vb[16];
    {
        s16x8 a = *(const s16x8*)(v0r + d0); s16x8 c = *(const s16x8*)(v0r + d0 + 8);
#pragma unroll
        for (int i = 0; i < 8; i++) { va[i] = bf2f(a[i]); va[8 + i] = bf2f(c[i]); }
        a = *(const s16x8*)(v1r + d0); c = *(const s16x8*)(v1r + d0 + 8);
#pragma unroll
        for (int i = 0; i < 8; i++) { vb[i] = bf2f(a[i]); vb[8 + i] = bf2f(c[i]); }
    }
    s16x8 pa, pb;
#pragma unroll
    for (int i = 0; i < 8; i++) {
        pa[i] = f2bf(w0 * va[i] + w1 * vb[i]);
        pb[i] = f2bf(w0 * va[8 + i] + w1 * vb[8 + i]);
    }
    short* o = ctx + (size_t)bq * DM + d0;
    *(s16x8*)o = pa;
    *(s16x8*)(o + 8) = pb;
}

// ---------------- LayerNorm over rows of 1024 ----------------
template<int OUTBF>
__global__ __launch_bounds__(256)
void ln_k(const float* __restrict__ in, const float* __restrict__ g,
          const float* __restrict__ bv, void* __restrict__ outp)
{
    const int row = blockIdx.x;
    const int tid = threadIdx.x;
    const float* x = in + (size_t)row * DM;
    const float4 v = *(const float4*)(x + tid * 4);
    float s = v.x + v.y + v.z + v.w;
    float ss = v.x * v.x + v.y * v.y + v.z * v.z + v.w * v.w;
#pragma unroll
    for (int m = 1; m < 64; m <<= 1) { s += __shfl_xor(s, m); ss += __shfl_xor(ss, m); }
    __shared__ float red[8];
    if ((tid & 63) == 0) { red[tid >> 6] = s; red[4 + (tid >> 6)] = ss; }
    __syncthreads();
    const float S = red[0] + red[1] + red[2] + red[3];
    const float SS = red[4] + red[5] + red[6] + red[7];
    const float mean = S * (1.f / DM);
    const float var = SS * (1.f / DM) - mean * mean;
    const float rstd = rsqrtf(var + 1e-5f);
    float y[4];
#pragma unroll
    for (int j = 0; j < 4; j++) {
        const int c = tid * 4 + j;
        const float xv = (j == 0) ? v.x : (j == 1) ? v.y : (j == 2) ? v.z : v.w;
        y[j] = (xv - mean) * rstd * g[c] + bv[c];
    }
    if (OUTBF) {
        s16x4 p; p[0] = f2bf(y[0]); p[1] = f2bf(y[1]); p[2] = f2bf(y[2]); p[3] = f2bf(y[3]);
        *(s16x4*)((short*)outp + (size_t)row * DM + tid * 4) = p;
    } else {
        float4 o; o.x = y[0]; o.y = y[1]; o.z = y[2]; o.w = y[3];
        *(float4*)((float*)outp + (size_t)row * DM + tid * 4) = o;
    }
}

extern "C" void kernel_launch(void* const* d_in, const int* in_sizes, int n_in,
                              void* d_out, int out_size, void* d_ws, size_t ws_size,
                              hipStream_t stream)
{
    const float* pred = (const float*)d_in[0];
    const float* ent  = (const float*)d_in[1];
    const int*   rel  = (const int*)d_in[2];
    const float* w_q  = (const float*)d_in[3];
    const float* b_q  = (const float*)d_in[4];
    const float* w_k  = (const float*)d_in[5];
    const float* b_k  = (const float*)d_in[6];
    const float* w_v  = (const float*)d_in[7];
    const float* b_v  = (const float*)d_in[8];
    const float* w_o  = (const float*)d_in[9];
    const float* b_o  = (const float*)d_in[10];
    const float* ln1g = (const float*)d_in[11];
    const float* ln1b = (const float*)d_in[12];
    const float* w1   = (const float*)d_in[13];
    const float* b1   = (const float*)d_in[14];
    const float* w2   = (const float*)d_in[15];
    const float* b2   = (const float*)d_in[16];
    const float* ln2g = (const float*)d_in[17];
    const float* ln2b = (const float*)d_in[18];

    char* ws = (char*)d_ws;
    size_t off = 0;
    auto alloc = [&](size_t bytes) -> char* {
        char* p = ws + off;
        off += (bytes + 255) & ~(size_t)255;
        return p;
    };
    short* wqT = (short*)alloc((size_t)1024 * 1024 * 2);
    short* wkT = (short*)alloc((size_t)1024 * 1024 * 2);
    short* wvT = (short*)alloc((size_t)1024 * 1024 * 2);
    short* woT = (short*)alloc((size_t)1024 * 1024 * 2);
    short* w1T = (short*)alloc((size_t)4096 * 1024 * 2);   // [4096][1024]
    short* w2T = (short*)alloc((size_t)1024 * 4096 * 2);   // [1024][4096]
    short* Kb  = (short*)alloc((size_t)BVTOT * DM * 2);
    short* Vb  = (short*)alloc((size_t)BVTOT * DM * 2);
    short* CTX = (short*)alloc((size_t)BQTOT * DM * 2);    // aliases: entB, Xb
    short* BIG = (short*)alloc((size_t)BQTOT * 2048 * 2);  // aliases: Qb+predB, then H0
    short* Qb    = BIG;                                    // first half
    short* predB = BIG + (size_t)BQTOT * DM;               // second half
    short* entB  = CTX;                                    // dead before attn writes CTX
    short* H0    = BIG;                                    // FFN hidden half (Qb/predB dead)
    short* Xb    = CTX;
    float* P     = (float*)d_out;   // fp32 pre-LN buffer lives in d_out

    // ---- activation fp32 -> bf16 converts ----
    conv_k<<<(BQTOT * DM / 8 + 255) / 256, 256, 0, stream>>>(pred, predB, BQTOT * DM / 8);
    conv_k<<<(BVTOT * DM / 8 + 255) / 256, 256, 0, stream>>>(ent, entB, BVTOT * DM / 8);

    // ---- weight transposes (fp32 -> bf16, [K][N] -> [N][K]) ----
    transp_k<<<dim3(32, 32), 256, 0, stream>>>(w_q, wqT, 1024, 1024);
    transp_k<<<dim3(32, 32), 256, 0, stream>>>(w_k, wkT, 1024, 1024);
    transp_k<<<dim3(32, 32), 256, 0, stream>>>(w_v, wvT, 1024, 1024);
    transp_k<<<dim3(32, 32), 256, 0, stream>>>(w_o, woT, 1024, 1024);
    transp_k<<<dim3(128, 32), 256, 0, stream>>>(w1, w1T, 1024, 4096);
    transp_k<<<dim3(32, 128), 256, 0, stream>>>(w2, w2T, 4096, 1024);

    // ---- projections (bf16 out) ----
    gemm2_k<0><<<2048, 256, 0, stream>>>(predB, wqT, b_q, nullptr, Qb,
                                         BQTOT, 1024, 1024, 1024, 1024, 8);
    gemm2_k<0><<<320, 256, 0, stream>>>(entB, wkT, b_k, nullptr, Kb,
                                        BVTOT, 1024, 1024, 1024, 1024, 8);
    gemm2_k<0><<<320, 256, 0, stream>>>(entB, wvT, b_v, nullptr, Vb,
                                        BVTOT, 1024, 1024, 1024, 1024, 8);

    // ---- sparse attention (2 allowed keys per query) ----
    attn_k<<<BQTOT, 64, 0, stream>>>(Qb, Kb, Vb, rel, CTX);

    // ---- output proj + residual -> P (f32), then LN1 -> Xb (bf16) ----
    gemm2_k<2><<<2048, 256, 0, stream>>>(CTX, woT, b_o, pred, P,
                                         BQTOT, 1024, 1024, 1024, 1024, 8);
    ln_k<1><<<BQTOT, 256, 0, stream>>>(P, ln1g, ln1b, Xb);

    // ---- FFN, split into two D_INNER halves ----
    gemm2_k<1><<<4096, 256, 0, stream>>>(Xb, w1T, b1, nullptr, H0,
                                         BQTOT, 2048, 1024, 1024, 1024, 16);
    gemm2_k<3><<<2048, 256, 0, stream>>>(H0, w2T, b2, Xb, P,
                                         BQTOT, 1024, 2048, 2048, 4096, 8);
    gemm2_k<1><<<4096, 256, 0, stream>>>(Xb, w1T + (size_t)2048 * 1024, b1 + 2048,
                                         nullptr, H0,
                                         BQTOT, 2048, 1024, 1024, 1024, 16);
    gemm2_k<4><<<2048, 256, 0, stream>>>(H0, w2T + 2048, b2, P, P,
                                         BQTOT, 1024, 2048, 2048, 4096, 8);

    // ---- LN2 in place -> d_out ----
    ln_k<0><<<BQTOT, 256, 0, stream>>>(P, ln2g, ln2b, P);
}

// Round 3
// 1152.677 us; speedup vs baseline: 1.2464x; 1.2293x over previous
//
#include <hip/hip_runtime.h>
#include <hip/hip_bf16.h>

#define DM 1024
#define QLEN 512
#define VLEN 80
#define BQTOT 32768   // B*Q
#define BVTOT 5120    // B*V

typedef __attribute__((ext_vector_type(8))) short s16x8;
typedef __attribute__((ext_vector_type(4))) short s16x4;
typedef __attribute__((ext_vector_type(4))) float f32x4;
typedef __attribute__((ext_vector_type(8))) __bf16 bf16x8;

__device__ inline short f2bf(float f) {
    __bf16 h = (__bf16)f;
    return __builtin_bit_cast(short, h);
}
__device__ inline float bf2f(short s) {
    unsigned u = ((unsigned)(unsigned short)s) << 16;
    return __builtin_bit_cast(float, u);
}

// ---------------- fp32 -> bf16 bulk convert (8 elems/thread) ----------------
__global__ __launch_bounds__(256)
void conv_k(const float* __restrict__ in, short* __restrict__ out, int n8)
{
    const int i = blockIdx.x * 256 + threadIdx.x;
    if (i >= n8) return;
    const float4 a = ((const float4*)in)[(size_t)i * 2];
    const float4 b = ((const float4*)in)[(size_t)i * 2 + 1];
    s16x8 p;
    p[0] = f2bf(a.x); p[1] = f2bf(a.y); p[2] = f2bf(a.z); p[3] = f2bf(a.w);
    p[4] = f2bf(b.x); p[5] = f2bf(b.y); p[6] = f2bf(b.z); p[7] = f2bf(b.w);
    ((s16x8*)out)[i] = p;
}

// ---------------- weight transpose + bf16 convert: W[K][N] -> WT[N][K] ----------------
__global__ __launch_bounds__(256)
void transp_k(const float* __restrict__ W, short* __restrict__ WT, int K, int N)
{
    __shared__ float s[32][33];
    const int n0 = blockIdx.x * 32, k0 = blockIdx.y * 32;
    const int tx = threadIdx.x & 31, ty = threadIdx.x >> 5;
#pragma unroll
    for (int j = 0; j < 4; j++)
        s[ty + j * 8][tx] = W[(size_t)(k0 + ty + j * 8) * N + n0 + tx];
    __syncthreads();
#pragma unroll
    for (int j = 0; j < 4; j++) {
        int r = ty + j * 8;
        WT[(size_t)(n0 + r) * K + k0 + tx] = f2bf(s[tx][r]);
    }
}

// ---------------- 256x256 deep-pipelined bf16 MFMA GEMM ----------------
// C[M][N] = A[M][K] * BT[N][K]^T (+ bias / residual per EPI)
// 512 threads = 8 waves (2M x 4N), per-wave 128x64 output, BK=64,
// double-buffered 128KB LDS, counted vmcnt(8) (2-tile prefetch),
// XOR-swizzled LDS (slot ^= row&7; pre-swizzled global source).
// EPI:  0 = bf16 out = acc+bias
//       1 = bf16 out = relu(acc+bias)
//       2 = f32 out = acc+bias+resid_f32
//       3 = f32 out = acc+bias+resid_bf16
//       4 = f32 out = acc+resid_f32 (no bias)

__device__ __forceinline__ void stage_tile(
    const short* __restrict__ A, const short* __restrict__ B,
    int lda, int ldb, int m0, int n0, int k0,
    short* AsB, short* BsB, int tid)
{
    const int r  = tid >> 3;              // 0..63 (row within 64-row stripe)
    const int sl = tid & 7;               // lds 16B slot
    const int sg = sl ^ (r & 7);          // inverse-swizzled source slot
    const int wid = tid >> 6;
#pragma unroll
    for (int i = 0; i < 4; i++) {
        const int row = i * 64 + r;
        __builtin_amdgcn_global_load_lds(
            (const __attribute__((address_space(1))) void*)(A + (size_t)(m0 + row) * lda + k0 + sg * 8),
            (__attribute__((address_space(3))) void*)(AsB + i * 4096 + wid * 512),
            16, 0, 0);
    }
#pragma unroll
    for (int i = 0; i < 4; i++) {
        const int row = i * 64 + r;
        __builtin_amdgcn_global_load_lds(
            (const __attribute__((address_space(1))) void*)(B + (size_t)(n0 + row) * ldb + k0 + sg * 8),
            (__attribute__((address_space(3))) void*)(BsB + i * 4096 + wid * 512),
            16, 0, 0);
    }
}

template<int EPI>
__global__ __launch_bounds__(512, 2)
void gemm3_k(const short* __restrict__ A, const short* __restrict__ BT,
             const float* __restrict__ bias, const void* __restrict__ resid,
             void* __restrict__ outp, int M, int N, int K, int lda, int ldb, int NT)
{
    __shared__ __align__(16) short As[2][256 * 64];   // 64 KB
    __shared__ __align__(16) short Bs[2][256 * 64];   // 64 KB

    const int tid = threadIdx.x;
    const int lane = tid & 63;
    const int wid = tid >> 6;
    const int wr = wid >> 2;       // 0..1
    const int wc = wid & 3;        // 0..3

    // bijective XCD swizzle (grid % 8 == 0 for all launches here)
    const int nwg = gridDim.x;
    const int f = blockIdx.x;
    const int logical = (f & 7) * (nwg >> 3) + (f >> 3);
    const int m0 = (logical / NT) * 256;
    const int n0 = (logical % NT) * 256;

    f32x4 acc[8][4];
#pragma unroll
    for (int i = 0; i < 8; i++)
#pragma unroll
        for (int j = 0; j < 4; j++) acc[i][j] = (f32x4){0.f, 0.f, 0.f, 0.f};

    const int NKT = K >> 6;
    // prologue: stage tiles 0 and 1
    stage_tile(A, BT, lda, ldb, m0, n0, 0,  As[0], Bs[0], tid);
    stage_tile(A, BT, lda, ldb, m0, n0, 64, As[1], Bs[1], tid);

    const int rowA0 = wr * 128 + (lane & 15);
    const int rowB0 = wc * 64 + (lane & 15);
    const int kgrp = lane >> 4;    // 0..3

    for (int t = 0; t < NKT; ++t) {
        if (t < NKT - 1) { asm volatile("s_waitcnt vmcnt(8)" ::: "memory"); }
        else             { asm volatile("s_waitcnt vmcnt(0)" ::: "memory"); }
        __builtin_amdgcn_sched_barrier(0);
        __builtin_amdgcn_s_barrier();
        __builtin_amdgcn_sched_barrier(0);

        const short* as = As[t & 1];
        const short* bs = Bs[t & 1];

        // B fragments: held for the whole tile
        bf16x8 bfr[4][2];
#pragma unroll
        for (int n = 0; n < 4; n++) {
            const int rb = rowB0 + n * 16;
#pragma unroll
            for (int ks = 0; ks < 2; ks++)
                bfr[n][ks] = *(const bf16x8*)&bs[rb * 64 + (((ks * 4 + kgrp) ^ (rb & 7)) << 3)];
        }
        // 4 quadrant phases: 2 m-frags x 4 n-frags x 2 ks = 16 MFMA each
#pragma unroll
        for (int q = 0; q < 4; ++q) {
            bf16x8 af[2][2];
#pragma unroll
            for (int mm = 0; mm < 2; mm++) {
                const int ra = rowA0 + (q * 2 + mm) * 16;
#pragma unroll
                for (int ks = 0; ks < 2; ks++)
                    af[mm][ks] = *(const bf16x8*)&as[ra * 64 + (((ks * 4 + kgrp) ^ (ra & 7)) << 3)];
            }
            __builtin_amdgcn_s_setprio(1);
#pragma unroll
            for (int mm = 0; mm < 2; mm++)
#pragma unroll
                for (int n = 0; n < 4; n++)
#pragma unroll
                    for (int ks = 0; ks < 2; ks++)
                        acc[q * 2 + mm][n] = __builtin_amdgcn_mfma_f32_16x16x32_bf16(
                            af[mm][ks], bfr[n][ks], acc[q * 2 + mm][n], 0, 0, 0);
            __builtin_amdgcn_s_setprio(0);
        }
        // drain this wave's LDS reads, then handoff barrier, then prefetch t+2
        asm volatile("s_waitcnt lgkmcnt(0)" ::: "memory");
        __builtin_amdgcn_sched_barrier(0);
        __builtin_amdgcn_s_barrier();
        __builtin_amdgcn_sched_barrier(0);
        if (t + 2 < NKT)
            stage_tile(A, BT, lda, ldb, m0, n0, (t + 2) * 64, As[t & 1], Bs[t & 1], tid);
    }

    // epilogue
    const int rbase = m0 + wr * 128 + ((lane >> 4) << 2);
    const int cbase = n0 + wc * 64 + (lane & 15);
#pragma unroll
    for (int mf = 0; mf < 8; ++mf) {
#pragma unroll
        for (int nf = 0; nf < 4; ++nf) {
            const int gn = cbase + nf * 16;
            const float bb = (EPI == 4) ? 0.f : bias[gn];
#pragma unroll
            for (int r = 0; r < 4; r++) {
                const int gm = rbase + mf * 16 + r;
                const size_t oidx = (size_t)gm * N + gn;
                float v = acc[mf][nf][r] + bb;
                if (EPI == 0) {
                    ((short*)outp)[oidx] = f2bf(v);
                } else if (EPI == 1) {
                    ((short*)outp)[oidx] = f2bf(fmaxf(v, 0.f));
                } else if (EPI == 2 || EPI == 4) {
                    ((float*)outp)[oidx] = v + ((const float*)resid)[oidx];
                } else { // EPI == 3
                    ((float*)outp)[oidx] = v + bf2f(((const short*)resid)[oidx]);
                }
            }
        }
    }
}

// ---------------- sparse 2-key attention gather ----------------
__global__ __launch_bounds__(64)
void attn_k(const short* __restrict__ Qb, const short* __restrict__ Kb,
            const short* __restrict__ Vb, const int* __restrict__ rel,
            short* __restrict__ ctx)
{
    const int bq = blockIdx.x;
    const int b = bq >> 9;           // Q = 512
    const int lane = threadIdx.x;
    const int v0 = rel[bq * 2 + 0];
    const int v1 = rel[bq * 2 + 1];
    const short* qr  = Qb + (size_t)bq * DM;
    const short* k0r = Kb + (size_t)(b * VLEN + v0) * DM;
    const short* k1r = Kb + (size_t)(b * VLEN + v1) * DM;
    const short* v0r = Vb + (size_t)(b * VLEN + v0) * DM;
    const short* v1r = Vb + (size_t)(b * VLEN + v1) * DM;
    const int d0 = lane * 16;

    float q[16], ka[16], kc[16];
    {
        s16x8 a = *(const s16x8*)(qr + d0);
        s16x8 c = *(const s16x8*)(qr + d0 + 8);
#pragma unroll
        for (int i = 0; i < 8; i++) { q[i] = bf2f(a[i]); q[8 + i] = bf2f(c[i]); }
        a = *(const s16x8*)(k0r + d0); c = *(const s16x8*)(k0r + d0 + 8);
#pragma unroll
        for (int i = 0; i < 8; i++) { ka[i] = bf2f(a[i]); ka[8 + i] = bf2f(c[i]); }
        a = *(const s16x8*)(k1r + d0); c = *(const s16x8*)(k1r + d0 + 8);
#pragma unroll
        for (int i = 0; i < 8; i++) { kc[i] = bf2f(a[i]); kc[8 + i] = bf2f(c[i]); }
    }
    float s0 = 0.f, s1 = 0.f;
#pragma unroll
    for (int i = 0; i < 16; i++) { s0 += q[i] * ka[i]; s1 += q[i] * kc[i]; }
#pragma unroll
    for (int m = 1; m < 8; m <<= 1) { s0 += __shfl_xor(s0, m); s1 += __shfl_xor(s1, m); }
    const float sc = 0.08838834764831845f; // 1/sqrt(128)
    s0 *= sc; s1 *= sc;
    const float mx = fmaxf(s0, s1);
    const float e0 = __expf(s0 - mx), e1 = __expf(s1 - mx);
    const float inv = 1.f / (e0 + e1);
    const float w0 = e0 * inv, w1 = e1 * inv;

    float va[16], vb[16];
    {
        s16x8 a = *(const s16x8*)(v0r + d0); s16x8 c = *(const s16x8*)(v0r + d0 + 8);
#pragma unroll
        for (int i = 0; i < 8; i++) { va[i] = bf2f(a[i]); va[8 + i] = bf2f(c[i]); }
        a = *(const s16x8*)(v1r + d0); c = *(const s16x8*)(v1r + d0 + 8);
#pragma unroll
        for (int i = 0; i < 8; i++) { vb[i] = bf2f(a[i]); vb[8 + i] = bf2f(c[i]); }
    }
    s16x8 pa, pb;
#pragma unroll
    for (int i = 0; i < 8; i++) {
        pa[i] = f2bf(w0 * va[i] + w1 * vb[i]);
        pb[i] = f2bf(w0 * va[8 + i] + w1 * vb[8 + i]);
    }
    short* o = ctx + (size_t)bq * DM + d0;
    *(s16x8*)o = pa;
    *(s16x8*)(o + 8) = pb;
}

// ---------------- LayerNorm over rows of 1024 ----------------
template<int OUTBF>
__global__ __launch_bounds__(256)
void ln_k(const float* __restrict__ in, const float* __restrict__ g,
          const float* __restrict__ bv, void* __restrict__ outp)
{
    const int row = blockIdx.x;
    const int tid = threadIdx.x;
    const float* x = in + (size_t)row * DM;
    const float4 v = *(const float4*)(x + tid * 4);
    float s = v.x + v.y + v.z + v.w;
    float ss = v.x * v.x + v.y * v.y + v.z * v.z + v.w * v.w;
#pragma unroll
    for (int m = 1; m < 64; m <<= 1) { s += __shfl_xor(s, m); ss += __shfl_xor(ss, m); }
    __shared__ float red[8];
    if ((tid & 63) == 0) { red[tid >> 6] = s; red[4 + (tid >> 6)] = ss; }
    __syncthreads();
    const float S = red[0] + red[1] + red[2] + red[3];
    const float SS = red[4] + red[5] + red[6] + red[7];
    const float mean = S * (1.f / DM);
    const float var = SS * (1.f / DM) - mean * mean;
    const float rstd = rsqrtf(var + 1e-5f);
    float y[4];
#pragma unroll
    for (int j = 0; j < 4; j++) {
        const int c = tid * 4 + j;
        const float xv = (j == 0) ? v.x : (j == 1) ? v.y : (j == 2) ? v.z : v.w;
        y[j] = (xv - mean) * rstd * g[c] + bv[c];
    }
    if (OUTBF) {
        s16x4 p; p[0] = f2bf(y[0]); p[1] = f2bf(y[1]); p[2] = f2bf(y[2]); p[3] = f2bf(y[3]);
        *(s16x4*)((short*)outp + (size_t)row * DM + tid * 4) = p;
    } else {
        float4 o; o.x = y[0]; o.y = y[1]; o.z = y[2]; o.w = y[3];
        *(float4*)((float*)outp + (size_t)row * DM + tid * 4) = o;
    }
}

extern "C" void kernel_launch(void* const* d_in, const int* in_sizes, int n_in,
                              void* d_out, int out_size, void* d_ws, size_t ws_size,
                              hipStream_t stream)
{
    const float* pred = (const float*)d_in[0];
    const float* ent  = (const float*)d_in[1];
    const int*   rel  = (const int*)d_in[2];
    const float* w_q  = (const float*)d_in[3];
    const float* b_q  = (const float*)d_in[4];
    const float* w_k  = (const float*)d_in[5];
    const float* b_k  = (const float*)d_in[6];
    const float* w_v  = (const float*)d_in[7];
    const float* b_v  = (const float*)d_in[8];
    const float* w_o  = (const float*)d_in[9];
    const float* b_o  = (const float*)d_in[10];
    const float* ln1g = (const float*)d_in[11];
    const float* ln1b = (const float*)d_in[12];
    const float* w1   = (const float*)d_in[13];
    const float* b1   = (const float*)d_in[14];
    const float* w2   = (const float*)d_in[15];
    const float* b2   = (const float*)d_in[16];
    const float* ln2g = (const float*)d_in[17];
    const float* ln2b = (const float*)d_in[18];

    char* ws = (char*)d_ws;
    size_t off = 0;
    auto alloc = [&](size_t bytes) -> char* {
        char* p = ws + off;
        off += (bytes + 255) & ~(size_t)255;
        return p;
    };
    short* wqT = (short*)alloc((size_t)1024 * 1024 * 2);
    short* wkT = (short*)alloc((size_t)1024 * 1024 * 2);
    short* wvT = (short*)alloc((size_t)1024 * 1024 * 2);
    short* woT = (short*)alloc((size_t)1024 * 1024 * 2);
    short* w1T = (short*)alloc((size_t)4096 * 1024 * 2);   // [4096][1024]
    short* w2T = (short*)alloc((size_t)1024 * 4096 * 2);   // [1024][4096]
    short* Kb  = (short*)alloc((size_t)BVTOT * DM * 2);
    short* Vb  = (short*)alloc((size_t)BVTOT * DM * 2);
    short* CTX = (short*)alloc((size_t)BQTOT * DM * 2);    // aliases: entB, Xb
    short* BIG = (short*)alloc((size_t)BQTOT * 2048 * 2);  // aliases: Qb+predB, then H0
    short* Qb    = BIG;                                    // first half
    short* predB = BIG + (size_t)BQTOT * DM;               // second half
    short* entB  = CTX;                                    // dead before attn writes CTX
    short* H0    = BIG;                                    // FFN hidden half (Qb/predB dead)
    short* Xb    = CTX;
    float* P     = (float*)d_out;   // fp32 pre-LN buffer lives in d_out

    // ---- activation fp32 -> bf16 converts ----
    conv_k<<<(BQTOT * DM / 8 + 255) / 256, 256, 0, stream>>>(pred, predB, BQTOT * DM / 8);
    conv_k<<<(BVTOT * DM / 8 + 255) / 256, 256, 0, stream>>>(ent, entB, BVTOT * DM / 8);

    // ---- weight transposes (fp32 -> bf16, [K][N] -> [N][K]) ----
    transp_k<<<dim3(32, 32), 256, 0, stream>>>(w_q, wqT, 1024, 1024);
    transp_k<<<dim3(32, 32), 256, 0, stream>>>(w_k, wkT, 1024, 1024);
    transp_k<<<dim3(32, 32), 256, 0, stream>>>(w_v, wvT, 1024, 1024);
    transp_k<<<dim3(32, 32), 256, 0, stream>>>(w_o, woT, 1024, 1024);
    transp_k<<<dim3(128, 32), 256, 0, stream>>>(w1, w1T, 1024, 4096);
    transp_k<<<dim3(32, 128), 256, 0, stream>>>(w2, w2T, 4096, 1024);

    // ---- projections (bf16 out), 256x256 tiles ----
    gemm3_k<0><<<512, 512, 0, stream>>>(predB, wqT, b_q, nullptr, Qb,
                                        BQTOT, 1024, 1024, 1024, 1024, 4);
    gemm3_k<0><<<80, 512, 0, stream>>>(entB, wkT, b_k, nullptr, Kb,
                                       BVTOT, 1024, 1024, 1024, 1024, 4);
    gemm3_k<0><<<80, 512, 0, stream>>>(entB, wvT, b_v, nullptr, Vb,
                                       BVTOT, 1024, 1024, 1024, 1024, 4);

    // ---- sparse attention (2 allowed keys per query) ----
    attn_k<<<BQTOT, 64, 0, stream>>>(Qb, Kb, Vb, rel, CTX);

    // ---- output proj + residual -> P (f32), then LN1 -> Xb (bf16) ----
    gemm3_k<2><<<512, 512, 0, stream>>>(CTX, woT, b_o, pred, P,
                                        BQTOT, 1024, 1024, 1024, 1024, 4);
    ln_k<1><<<BQTOT, 256, 0, stream>>>(P, ln1g, ln1b, Xb);

    // ---- FFN, split into two D_INNER halves ----
    gemm3_k<1><<<1024, 512, 0, stream>>>(Xb, w1T, b1, nullptr, H0,
                                         BQTOT, 2048, 1024, 1024, 1024, 8);
    gemm3_k<3><<<512, 512, 0, stream>>>(H0, w2T, b2, Xb, P,
                                        BQTOT, 1024, 2048, 2048, 4096, 4);
    gemm3_k<1><<<1024, 512, 0, stream>>>(Xb, w1T + (size_t)2048 * 1024, b1 + 2048,
                                         nullptr, H0,
                                         BQTOT, 2048, 1024, 1024, 1024, 8);
    gemm3_k<4><<<512, 512, 0, stream>>>(H0, w2T + 2048, b2, P, P,
                                        BQTOT, 1024, 2048, 2048, 4096, 4);

    // ---- LN2 in place -> d_out ----
    ln_k<0><<<BQTOT, 256, 0, stream>>>(P, ln2g, ln2b, P);
}

// Round 4
// 1108.916 us; speedup vs baseline: 1.2956x; 1.0395x over previous
//
#include <hip/hip_runtime.h>
#include <hip/hip_bf16.h>

#define DM 1024
#define QLEN 512
#define VLEN 80
#define BQTOT 32768   // B*Q
#define BVTOT 5120    // B*V

typedef __attribute__((ext_vector_type(8))) short s16x8;
typedef __attribute__((ext_vector_type(4))) short s16x4;
typedef __attribute__((ext_vector_type(4))) float f32x4;
typedef __attribute__((ext_vector_type(8))) __bf16 bf16x8;

__device__ inline short f2bf(float f) {
    __bf16 h = (__bf16)f;
    return __builtin_bit_cast(short, h);
}
__device__ inline float bf2f(short s) {
    unsigned u = ((unsigned)(unsigned short)s) << 16;
    return __builtin_bit_cast(float, u);
}

// ---------------- fp32 -> bf16 bulk convert (8 elems/thread) ----------------
__global__ __launch_bounds__(256)
void conv_k(const float* __restrict__ in, short* __restrict__ out, int n8)
{
    const int i = blockIdx.x * 256 + threadIdx.x;
    if (i >= n8) return;
    const float4 a = ((const float4*)in)[(size_t)i * 2];
    const float4 b = ((const float4*)in)[(size_t)i * 2 + 1];
    s16x8 p;
    p[0] = f2bf(a.x); p[1] = f2bf(a.y); p[2] = f2bf(a.z); p[3] = f2bf(a.w);
    p[4] = f2bf(b.x); p[5] = f2bf(b.y); p[6] = f2bf(b.z); p[7] = f2bf(b.w);
    ((s16x8*)out)[i] = p;
}

// ---------------- weight transpose + bf16 convert: W[K][N] -> WT[N][K] ----------------
__global__ __launch_bounds__(256)
void transp_k(const float* __restrict__ W, short* __restrict__ WT, int K, int N)
{
    __shared__ float s[32][33];
    const int n0 = blockIdx.x * 32, k0 = blockIdx.y * 32;
    const int tx = threadIdx.x & 31, ty = threadIdx.x >> 5;
#pragma unroll
    for (int j = 0; j < 4; j++)
        s[ty + j * 8][tx] = W[(size_t)(k0 + ty + j * 8) * N + n0 + tx];
    __syncthreads();
#pragma unroll
    for (int j = 0; j < 4; j++) {
        int r = ty + j * 8;
        WT[(size_t)(n0 + r) * K + k0 + tx] = f2bf(s[tx][r]);
    }
}

// ---------------- 256x256 8-phase bf16 MFMA GEMM (m201-style) ----------------
// C[M][N] = A[M][K] * BT[N][K]^T (+ bias / residual per EPI)
// 512 threads = 8 waves (2M x 4N), wave tile 128x64, BK=64.
// LDS: per matrix 2 bufs (K-tile parity) x 2 halves x [128x64], XOR-swizzled.
// 8 phases per 2 K-tiles; counted vmcnt(4) at phases 4/8; never 0 in steady state.
// EPI:  0 = bf16 out = acc+bias
//       1 = bf16 out = relu(acc+bias)
//       2 = f32 out = acc+bias+resid_f32
//       3 = f32 out = acc+bias+resid_bf16
//       4 = f32 out = acc+resid_f32 (no bias)

__device__ __forceinline__ void stage_chunk(const short* __restrict__ src, int ld,
                                            int row0, int k0, short* dst, int tid)
{
    // chunk = 128 rows x 64 cols, linear LDS dest, inverse-swizzled global source
    const int w = tid >> 6, lane = tid & 63;
#pragma unroll
    for (int j = 0; j < 2; j++) {
        const int r = w * 16 + j * 8 + (lane >> 3);            // 0..127
        const int sg = (lane & 7) ^ (r & 7);
        __builtin_amdgcn_global_load_lds(
            (const __attribute__((address_space(1))) void*)(src + (size_t)(row0 + r) * ld + k0 + sg * 8),
            (__attribute__((address_space(3))) void*)(dst + w * 1024 + j * 512),
            16, 0, 0);
    }
}

#define READ_B(db) do { \
    _Pragma("unroll") for (int n = 0; n < 4; n++) { \
        const int lb = ((wc & 1) << 6) + la15 + n * 16; \
        _Pragma("unroll") for (int ks = 0; ks < 2; ks++) \
            bfr[n][ks] = *(const bf16x8*)&Bs[db][wc >> 1][lb * 64 + kx[ks]]; \
    } } while (0)

#define READ_A(db, q) do { \
    _Pragma("unroll") for (int mm = 0; mm < 2; mm++) { \
        const int lr2 = la15 + ((q) * 2 + mm) * 16; \
        _Pragma("unroll") for (int ks = 0; ks < 2; ks++) \
            af[mm][ks] = *(const bf16x8*)&As[db][wr][lr2 * 64 + kx[ks]]; \
    } } while (0)

#define MFMA16(q) do { \
    __builtin_amdgcn_s_setprio(1); \
    _Pragma("unroll") for (int mm = 0; mm < 2; mm++) \
    _Pragma("unroll") for (int n = 0; n < 4; n++) \
    _Pragma("unroll") for (int ks = 0; ks < 2; ks++) \
        acc[(q) * 2 + mm][n] = __builtin_amdgcn_mfma_f32_16x16x32_bf16( \
            af[mm][ks], bfr[n][ks], acc[(q) * 2 + mm][n], 0, 0, 0); \
    __builtin_amdgcn_s_setprio(0); \
} while (0)

#define OPEN_PHASE() do { \
    __builtin_amdgcn_s_barrier(); \
    asm volatile("s_waitcnt lgkmcnt(0)" ::: "memory"); \
    __builtin_amdgcn_sched_barrier(0); \
} while (0)

template<int EPI>
__global__ __launch_bounds__(512, 2)
void gemm4_k(const short* __restrict__ A, const short* __restrict__ BT,
             const float* __restrict__ bias, const void* __restrict__ resid,
             void* __restrict__ outp, int M, int N, int K, int lda, int ldb, int NT)
{
    __shared__ __align__(16) short As[2][2][8192];   // [kt parity][half][128*64]
    __shared__ __align__(16) short Bs[2][2][8192];

    const int tid = threadIdx.x;
    const int lane = tid & 63;
    const int wid = tid >> 6;
    const int wr = wid >> 2, wc = wid & 3;

    // bijective XCD swizzle (grid % 8 == 0 for all launches here)
    const int nwg = gridDim.x;
    const int fb = blockIdx.x;
    const int logical = (fb & 7) * (nwg >> 3) + (fb >> 3);
    const int m0 = (logical / NT) * 256;
    const int n0 = (logical % NT) * 256;

    f32x4 acc[8][4];
#pragma unroll
    for (int i = 0; i < 8; i++)
#pragma unroll
        for (int j = 0; j < 4; j++) acc[i][j] = (f32x4){0.f, 0.f, 0.f, 0.f};

    const short* Ab = A + (size_t)m0 * lda;
    const short* Bb = BT + (size_t)n0 * ldb;

    const int kgrp = lane >> 4;
    const int la15 = lane & 15;
    int kx[2];
    kx[0] = ((kgrp)     ^ (lane & 7)) << 3;
    kx[1] = ((4 + kgrp) ^ (lane & 7)) << 3;

    // prologue: A(0) both halves, B(0), B(1)
    stage_chunk(Ab, lda, 0,   0,  As[0][0], tid);
    stage_chunk(Ab, lda, 128, 0,  As[0][1], tid);
    stage_chunk(Bb, ldb, 0,   0,  Bs[0][0], tid);
    stage_chunk(Bb, ldb, 128, 0,  Bs[0][1], tid);
    stage_chunk(Bb, ldb, 0,   64, Bs[1][0], tid);
    stage_chunk(Bb, ldb, 128, 64, Bs[1][1], tid);
    asm volatile("s_waitcnt vmcnt(4)" ::: "memory");
    __builtin_amdgcn_sched_barrier(0);
    __builtin_amdgcn_s_barrier();

    const int NP = K >> 7;   // iterations; each covers 2 K-tiles
    for (int I = 0; I < NP; ++I) {
        const int T = 2 * I;
        const bool nl = (I + 1 < NP);   // notLast (wave-uniform)
        bf16x8 bfr[4][2], af[2][2];

        // ---- phase 1: tile T (buf0) q0 ; stage A-h0(T+1) -> As[1][0]
        READ_B(0); READ_A(0, 0);
        stage_chunk(Ab, lda, 0, (T + 1) * 64, As[1][0], tid);
        asm volatile("s_waitcnt lgkmcnt(8)" ::: "memory");
        OPEN_PHASE();
        MFMA16(0);
        // ---- phase 2: q1 ; stage A-h1(T+1) -> As[1][1]
        __builtin_amdgcn_s_barrier();
        READ_A(0, 1);
        stage_chunk(Ab, lda, 128, (T + 1) * 64, As[1][1], tid);
        OPEN_PHASE();
        MFMA16(1);
        // ---- phase 3: q2 ; stage B-h0(T+2) -> Bs[0][0]
        __builtin_amdgcn_s_barrier();
        READ_A(0, 2);
        if (nl) stage_chunk(Bb, ldb, 0, (T + 2) * 64, Bs[0][0], tid);
        OPEN_PHASE();
        MFMA16(2);
        // ---- phase 4: q3 ; stage B-h1(T+2) -> Bs[0][1] ; guard G1
        __builtin_amdgcn_s_barrier();
        READ_A(0, 3);
        if (nl) stage_chunk(Bb, ldb, 128, (T + 2) * 64, Bs[0][1], tid);
        OPEN_PHASE();
        MFMA16(3);
        if (nl) { asm volatile("s_waitcnt vmcnt(4)" ::: "memory"); }
        else    { asm volatile("s_waitcnt vmcnt(0)" ::: "memory"); }
        __builtin_amdgcn_sched_barrier(0);
        // ---- phase 5: tile T+1 (buf1) q0 ; stage A-h0(T+2) -> As[0][0]
        __builtin_amdgcn_s_barrier();
        READ_B(1); READ_A(1, 0);
        if (nl) stage_chunk(Ab, lda, 0, (T + 2) * 64, As[0][0], tid);
        asm volatile("s_waitcnt lgkmcnt(8)" ::: "memory");
        OPEN_PHASE();
        MFMA16(0);
        // ---- phase 6: q1 ; stage A-h1(T+2) -> As[0][1]
        __builtin_amdgcn_s_barrier();
        READ_A(1, 1);
        if (nl) stage_chunk(Ab, lda, 128, (T + 2) * 64, As[0][1], tid);
        OPEN_PHASE();
        MFMA16(1);
        // ---- phase 7: q2 ; stage B-h0(T+3) -> Bs[1][0]
        __builtin_amdgcn_s_barrier();
        READ_A(1, 2);
        if (nl) stage_chunk(Bb, ldb, 0, (T + 3) * 64, Bs[1][0], tid);
        OPEN_PHASE();
        MFMA16(2);
        // ---- phase 8: q3 ; stage B-h1(T+3) -> Bs[1][1] ; guard G2
        __builtin_amdgcn_s_barrier();
        READ_A(1, 3);
        if (nl) stage_chunk(Bb, ldb, 128, (T + 3) * 64, Bs[1][1], tid);
        OPEN_PHASE();
        MFMA16(3);
        if (nl) {
            asm volatile("s_waitcnt vmcnt(4)" ::: "memory");
            __builtin_amdgcn_sched_barrier(0);
            __builtin_amdgcn_s_barrier();
        }
    }

    // epilogue
    const int rbase = m0 + wr * 128 + ((lane >> 4) << 2);
    const int cbase = n0 + wc * 64 + la15;
#pragma unroll
    for (int mf = 0; mf < 8; ++mf) {
#pragma unroll
        for (int nf = 0; nf < 4; ++nf) {
            const int gn = cbase + nf * 16;
            const float bb = (EPI == 4) ? 0.f : bias[gn];
#pragma unroll
            for (int r = 0; r < 4; r++) {
                const int gm = rbase + mf * 16 + r;
                const size_t oidx = (size_t)gm * N + gn;
                float v = acc[mf][nf][r] + bb;
                if (EPI == 0) {
                    ((short*)outp)[oidx] = f2bf(v);
                } else if (EPI == 1) {
                    ((short*)outp)[oidx] = f2bf(fmaxf(v, 0.f));
                } else if (EPI == 2 || EPI == 4) {
                    ((float*)outp)[oidx] = v + ((const float*)resid)[oidx];
                } else { // EPI == 3
                    ((float*)outp)[oidx] = v + bf2f(((const short*)resid)[oidx]);
                }
            }
        }
    }
}

// ---------------- sparse 2-key attention gather ----------------
__global__ __launch_bounds__(64)
void attn_k(const short* __restrict__ Qb, const short* __restrict__ Kb,
            const short* __restrict__ Vb, const int* __restrict__ rel,
            short* __restrict__ ctx)
{
    const int bq = blockIdx.x;
    const int b = bq >> 9;           // Q = 512
    const int lane = threadIdx.x;
    const int v0 = rel[bq * 2 + 0];
    const int v1 = rel[bq * 2 + 1];
    const short* qr  = Qb + (size_t)bq * DM;
    const short* k0r = Kb + (size_t)(b * VLEN + v0) * DM;
    const short* k1r = Kb + (size_t)(b * VLEN + v1) * DM;
    const short* v0r = Vb + (size_t)(b * VLEN + v0) * DM;
    const short* v1r = Vb + (size_t)(b * VLEN + v1) * DM;
    const int d0 = lane * 16;

    float q[16], ka[16], kc[16];
    {
        s16x8 a = *(const s16x8*)(qr + d0);
        s16x8 c = *(const s16x8*)(qr + d0 + 8);
#pragma unroll
        for (int i = 0; i < 8; i++) { q[i] = bf2f(a[i]); q[8 + i] = bf2f(c[i]); }
        a = *(const s16x8*)(k0r + d0); c = *(const s16x8*)(k0r + d0 + 8);
#pragma unroll
        for (int i = 0; i < 8; i++) { ka[i] = bf2f(a[i]); ka[8 + i] = bf2f(c[i]); }
        a = *(const s16x8*)(k1r + d0); c = *(const s16x8*)(k1r + d0 + 8);
#pragma unroll
        for (int i = 0; i < 8; i++) { kc[i] = bf2f(a[i]); kc[8 + i] = bf2f(c[i]); }
    }
    float s0 = 0.f, s1 = 0.f;
#pragma unroll
    for (int i = 0; i < 16; i++) { s0 += q[i] * ka[i]; s1 += q[i] * kc[i]; }
#pragma unroll
    for (int m = 1; m < 8; m <<= 1) { s0 += __shfl_xor(s0, m); s1 += __shfl_xor(s1, m); }
    const float sc = 0.08838834764831845f; // 1/sqrt(128)
    s0 *= sc; s1 *= sc;
    const float mx = fmaxf(s0, s1);
    const float e0 = __expf(s0 - mx), e1 = __expf(s1 - mx);
    const float inv = 1.f / (e0 + e1);
    const float w0 = e0 * inv, w1 = e1 * inv;

    float va[16], vb[16];
    {
        s16x8 a = *(const s16x8*)(v0r + d0); s16x8 c = *(const s16x8*)(v0r + d0 + 8);
#pragma unroll
        for (int i = 0; i < 8; i++) { va[i] = bf2f(a[i]); va[8 + i] = bf2f(c[i]); }
        a = *(const s16x8*)(v1r + d0); c = *(const s16x8*)(v1r + d0 + 8);
#pragma unroll
        for (int i = 0; i < 8; i++) { vb[i] = bf2f(a[i]); vb[8 + i] = bf2f(c[i]); }
    }
    s16x8 pa, pb;
#pragma unroll
    for (int i = 0; i < 8; i++) {
        pa[i] = f2bf(w0 * va[i] + w1 * vb[i]);
        pb[i] = f2bf(w0 * va[8 + i] + w1 * vb[8 + i]);
    }
    short* o = ctx + (size_t)bq * DM + d0;
    *(s16x8*)o = pa;
    *(s16x8*)(o + 8) = pb;
}

// ---------------- LayerNorm over rows of 1024 ----------------
template<int OUTBF>
__global__ __launch_bounds__(256)
void ln_k(const float* __restrict__ in, const float* __restrict__ g,
          const float* __restrict__ bv, void* __restrict__ outp)
{
    const int row = blockIdx.x;
    const int tid = threadIdx.x;
    const float* x = in + (size_t)row * DM;
    const float4 v = *(const float4*)(x + tid * 4);
    float s = v.x + v.y + v.z + v.w;
    float ss = v.x * v.x + v.y * v.y + v.z * v.z + v.w * v.w;
#pragma unroll
    for (int m = 1; m < 64; m <<= 1) { s += __shfl_xor(s, m); ss += __shfl_xor(ss, m); }
    __shared__ float red[8];
    if ((tid & 63) == 0) { red[tid >> 6] = s; red[4 + (tid >> 6)] = ss; }
    __syncthreads();
    const float S = red[0] + red[1] + red[2] + red[3];
    const float SS = red[4] + red[5] + red[6] + red[7];
    const float mean = S * (1.f / DM);
    const float var = SS * (1.f / DM) - mean * mean;
    const float rstd = rsqrtf(var + 1e-5f);
    float y[4];
#pragma unroll
    for (int j = 0; j < 4; j++) {
        const int c = tid * 4 + j;
        const float xv = (j == 0) ? v.x : (j == 1) ? v.y : (j == 2) ? v.z : v.w;
        y[j] = (xv - mean) * rstd * g[c] + bv[c];
    }
    if (OUTBF) {
        s16x4 p; p[0] = f2bf(y[0]); p[1] = f2bf(y[1]); p[2] = f2bf(y[2]); p[3] = f2bf(y[3]);
        *(s16x4*)((short*)outp + (size_t)row * DM + tid * 4) = p;
    } else {
        float4 o; o.x = y[0]; o.y = y[1]; o.z = y[2]; o.w = y[3];
        *(float4*)((float*)outp + (size_t)row * DM + tid * 4) = o;
    }
}

extern "C" void kernel_launch(void* const* d_in, const int* in_sizes, int n_in,
                              void* d_out, int out_size, void* d_ws, size_t ws_size,
                              hipStream_t stream)
{
    const float* pred = (const float*)d_in[0];
    const float* ent  = (const float*)d_in[1];
    const int*   rel  = (const int*)d_in[2];
    const float* w_q  = (const float*)d_in[3];
    const float* b_q  = (const float*)d_in[4];
    const float* w_k  = (const float*)d_in[5];
    const float* b_k  = (const float*)d_in[6];
    const float* w_v  = (const float*)d_in[7];
    const float* b_v  = (const float*)d_in[8];
    const float* w_o  = (const float*)d_in[9];
    const float* b_o  = (const float*)d_in[10];
    const float* ln1g = (const float*)d_in[11];
    const float* ln1b = (const float*)d_in[12];
    const float* w1   = (const float*)d_in[13];
    const float* b1   = (const float*)d_in[14];
    const float* w2   = (const float*)d_in[15];
    const float* b2   = (const float*)d_in[16];
    const float* ln2g = (const float*)d_in[17];
    const float* ln2b = (const float*)d_in[18];

    char* ws = (char*)d_ws;
    size_t off = 0;
    auto alloc = [&](size_t bytes) -> char* {
        char* p = ws + off;
        off += (bytes + 255) & ~(size_t)255;
        return p;
    };
    short* wqT = (short*)alloc((size_t)1024 * 1024 * 2);
    short* wkT = (short*)alloc((size_t)1024 * 1024 * 2);
    short* wvT = (short*)alloc((size_t)1024 * 1024 * 2);
    short* woT = (short*)alloc((size_t)1024 * 1024 * 2);
    short* w1T = (short*)alloc((size_t)4096 * 1024 * 2);   // [4096][1024]
    short* w2T = (short*)alloc((size_t)1024 * 4096 * 2);   // [1024][4096]
    short* Kb  = (short*)alloc((size_t)BVTOT * DM * 2);
    short* Vb  = (short*)alloc((size_t)BVTOT * DM * 2);
    short* CTX = (short*)alloc((size_t)BQTOT * DM * 2);    // aliases: entB, Xb
    short* BIG = (short*)alloc((size_t)BQTOT * 2048 * 2);  // aliases: Qb+predB, then H0
    short* Qb    = BIG;                                    // first half
    short* predB = BIG + (size_t)BQTOT * DM;               // second half
    short* entB  = CTX;                                    // dead before attn writes CTX
    short* H0    = BIG;                                    // FFN hidden half (Qb/predB dead)
    short* Xb    = CTX;
    float* P     = (float*)d_out;   // fp32 pre-LN buffer lives in d_out

    // ---- activation fp32 -> bf16 converts ----
    conv_k<<<(BQTOT * DM / 8 + 255) / 256, 256, 0, stream>>>(pred, predB, BQTOT * DM / 8);
    conv_k<<<(BVTOT * DM / 8 + 255) / 256, 256, 0, stream>>>(ent, entB, BVTOT * DM / 8);

    // ---- weight transposes (fp32 -> bf16, [K][N] -> [N][K]) ----
    transp_k<<<dim3(32, 32), 256, 0, stream>>>(w_q, wqT, 1024, 1024);
    transp_k<<<dim3(32, 32), 256, 0, stream>>>(w_k, wkT, 1024, 1024);
    transp_k<<<dim3(32, 32), 256, 0, stream>>>(w_v, wvT, 1024, 1024);
    transp_k<<<dim3(32, 32), 256, 0, stream>>>(w_o, woT, 1024, 1024);
    transp_k<<<dim3(128, 32), 256, 0, stream>>>(w1, w1T, 1024, 4096);
    transp_k<<<dim3(32, 128), 256, 0, stream>>>(w2, w2T, 4096, 1024);

    // ---- projections (bf16 out), 256x256 tiles ----
    gemm4_k<0><<<512, 512, 0, stream>>>(predB, wqT, b_q, nullptr, Qb,
                                        BQTOT, 1024, 1024, 1024, 1024, 4);
    gemm4_k<0><<<80, 512, 0, stream>>>(entB, wkT, b_k, nullptr, Kb,
                                       BVTOT, 1024, 1024, 1024, 1024, 4);
    gemm4_k<0><<<80, 512, 0, stream>>>(entB, wvT, b_v, nullptr, Vb,
                                       BVTOT, 1024, 1024, 1024, 1024, 4);

    // ---- sparse attention (2 allowed keys per query) ----
    attn_k<<<BQTOT, 64, 0, stream>>>(Qb, Kb, Vb, rel, CTX);

    // ---- output proj + residual -> P (f32), then LN1 -> Xb (bf16) ----
    gemm4_k<2><<<512, 512, 0, stream>>>(CTX, woT, b_o, pred, P,
                                        BQTOT, 1024, 1024, 1024, 1024, 4);
    ln_k<1><<<BQTOT, 256, 0, stream>>>(P, ln1g, ln1b, Xb);

    // ---- FFN, split into two D_INNER halves ----
    gemm4_k<1><<<1024, 512, 0, stream>>>(Xb, w1T, b1, nullptr, H0,
                                         BQTOT, 2048, 1024, 1024, 1024, 8);
    gemm4_k<3><<<512, 512, 0, stream>>>(H0, w2T, b2, Xb, P,
                                        BQTOT, 1024, 2048, 2048, 4096, 4);
    gemm4_k<1><<<1024, 512, 0, stream>>>(Xb, w1T + (size_t)2048 * 1024, b1 + 2048,
                                         nullptr, H0,
                                         BQTOT, 2048, 1024, 1024, 1024, 8);
    gemm4_k<4><<<512, 512, 0, stream>>>(H0, w2T + 2048, b2, P, P,
                                        BQTOT, 1024, 2048, 2048, 4096, 4);

    // ---- LN2 in place -> d_out ----
    ln_k<0><<<BQTOT, 256, 0, stream>>>(P, ln2g, ln2b, P);
}